// Round 4
// baseline (592.190 us; speedup 1.0000x reference)
//
#include <hip/hip_runtime.h>
#include <cstdint>
#include <cstddef>

// ---------------- constants ----------------
#define S_IMG   3136            // 56*56
#define PPOS    3364            // 58*58 padded positions
#define PLANE_B (PPOS * 16)     // 53824 bytes per (b,cc,kblk) plane
#define XPAD_BYTES (32 * 8 * 4 * PLANE_B)        // 55,115,776
#define WT2_OFF    XPAD_BYTES
#define WT2_BYTES  (9 * 8 * 4 * 256 * 16)        // 1,179,648
#define STATS_OFF  (WT2_OFF + WT2_BYTES)         // 56,295,424
// stats region (floats): Sb[32*256] @0, sumsq[256] @8192, bias[32*256] @8448,
//                        scale[256] @16640, shiftb[32*256] @16896  (25088 total)

typedef __bf16 bf16x8 __attribute__((ext_vector_type(8)));
typedef short  s16x8  __attribute__((ext_vector_type(8)));
typedef float  f32x4  __attribute__((ext_vector_type(4)));

__device__ __forceinline__ unsigned short f2bf(float f) {
    unsigned u = __float_as_uint(f);
    u += 0x7fffu + ((u >> 16) & 1u);   // round-to-nearest-even
    return (unsigned short)(u >> 16);
}

__device__ __forceinline__ void gll16(const void* g, void* l) {
    __builtin_amdgcn_global_load_lds(
        (const __attribute__((address_space(1))) void*)g,
        (__attribute__((address_space(3))) void*)l, 16, 0, 0);
}

// ---------------- K1a: zero pad ring + stats, W transpose, bias GEMV ----------
// grid 1265 blocks: [0,945) zero, [945,1233) prep_w, [1233,1265) prep_bias
__global__ __launch_bounds__(256) void prep_small(const float* __restrict__ W,
                                                  const float* __restrict__ gate,
                                                  const float* __restrict__ be,
                                                  char* __restrict__ xpad,
                                                  char* __restrict__ wt2,
                                                  float* __restrict__ stats) {
    const int blk = blockIdx.x;
    if (blk < 945) {
        const int t = blk * 256 + threadIdx.x;    // < 241920
        if (t < 1024 * 228) {                     // 1024 planes * 228 pad positions
            const int plane = t / 228, pi = t % 228;
            int pos;
            if (pi < 58)       pos = pi;                       // top row
            else if (pi < 116) pos = 3306 + (pi - 58);         // bottom row
            else { const int q = pi - 116; pos = ((q >> 1) + 1) * 58 + (q & 1) * 57; }
            *(uint4*)(xpad + (size_t)plane * PLANE_B + (size_t)pos * 16) =
                make_uint4(0u, 0u, 0u, 0u);
        } else {
            stats[t - 1024 * 228] = 0.f;          // Sb[8192] + sumsq[256]
        }
    } else if (blk < 1233) {
        const int g = (blk - 945) * 256 + threadIdx.x;
        if (g >= 9 * 256 * 32) return;
        const int ci8 = g % 32;                   // = cc*4 + kblk
        const int co  = (g / 32) % 256;
        const int tap = g / (32 * 256);
        const float* src = W + ((size_t)co * 256 + ci8 * 8) * 9 + tap;
        unsigned short v[8];
#pragma unroll
        for (int j = 0; j < 8; ++j) v[j] = f2bf(src[j * 9]);
        uint4 o;
        o.x = (unsigned)v[0] | ((unsigned)v[1] << 16);
        o.y = (unsigned)v[2] | ((unsigned)v[3] << 16);
        o.z = (unsigned)v[4] | ((unsigned)v[5] << 16);
        o.w = (unsigned)v[6] | ((unsigned)v[7] << 16);
        *(uint4*)(wt2 + ((size_t)(tap * 32 + ci8) * 256 + co) * 16) = o;
    } else {
        const int b = blk - 1233, co = threadIdx.x;
        const float* gb = gate + b * 256;
        float s = 0.f;
        for (int ci = 0; ci < 256; ++ci) s += gb[ci] * be[ci * 256 + co];
        stats[8448 + b * 256 + co] = s;           // bias[b][co]
    }
}

// ---------------- K1b: x*gate -> bf16, NCHW -> padded [b][cc][kblk][pos][8ci] ----
__global__ __launch_bounds__(256) void prep_x(const float* __restrict__ x,
                                              const float* __restrict__ gate,
                                              char* __restrict__ xpad) {
    __shared__ unsigned short xb[14336];      // [256 ci][56 w] bf16
    const int tid = threadIdx.x;
    const int b = blockIdx.x / 56, h = blockIdx.x % 56;
    const float* xbase = x + (size_t)b * 256 * S_IMG + h * 56;
    const float* gb = gate + b * 256;
#pragma unroll
    for (int i = 0; i < 14; ++i) {
        const int e4 = i * 1024 + tid * 4;    // flattened (ci*56 + w), w%4==0
        const int ci = e4 / 56, w = e4 % 56;
        const float4 v = *(const float4*)(xbase + (size_t)ci * S_IMG + w);
        const float g = gb[ci];
        ushort4 o;
        o.x = f2bf(v.x * g); o.y = f2bf(v.y * g);
        o.z = f2bf(v.z * g); o.w = f2bf(v.w * g);
        *(ushort4*)(xb + e4) = o;
    }
    __syncthreads();
    char* dst_b = xpad + (size_t)b * 32 * PLANE_B + ((size_t)((h + 1) * 58 + 1)) * 16;
#pragma unroll
    for (int i = 0; i < 7; ++i) {
        const int c = i * 256 + tid;          // 1792 chunks of 16B
        const int pw = c % 56, cg = c / 56;   // cg = cc*4 + kblk  (ci group of 8)
        const unsigned short* src = xb + cg * 8 * 56 + pw;
        uint4 o;
        o.x = (unsigned)src[0]   | ((unsigned)src[56]  << 16);
        o.y = (unsigned)src[112] | ((unsigned)src[168] << 16);
        o.z = (unsigned)src[224] | ((unsigned)src[280] << 16);
        o.w = (unsigned)src[336] | ((unsigned)src[392] << 16);
        *(uint4*)(dst_b + (size_t)cg * PLANE_B + (size_t)pw * 16) = o;
    }
}

// ---------------- K2: implicit-GEMM conv, 256x256 tile, 8-phase schedule -------
// grid 392 blocks (XCD-swizzled, 392 = 8*49), 512 threads (8 waves = 2M x 4N).
// BK=64 = 2 cc-chunks x (4 kblk x 8 ci). 36 K-tiles (tap inner: t = cp*9 + tap).
// LDS 128KB = 2 buffers x [A 32KB | B 32KB]; buffer layout:
//   A: cc'*16384 + kblk*4096 + co*16    B: 32768 + cc'*16384 + kblk*4096 + gsl*16
// Staging quarters per tile: Q0=A.cc'0, Q2=B.cc'0, Q1=A.cc'1, Q3=B.cc'1
// (2 gll16/thread/phase; vmcnt(4) twice per tile, never 0 in-loop).
__global__ __launch_bounds__(512, 1) void conv_mfma(
    const char* __restrict__ xpad, const char* __restrict__ wt2,
    float* __restrict__ y, float* __restrict__ Sb, float* __restrict__ sumsq) {
    extern __shared__ char smem[];            // 131072
    const int tid = threadIdx.x;
    const int lane = tid & 63, w = tid >> 6;
    const int wm = w >> 2, wn = w & 3;

    const int L = blockIdx.x;                 // XCD swizzle: 392 = 8*49
    const int s0 = ((L & 7) * 49 + (L >> 3)) * 256;

    // ---- per-thread staging constants ----
    const int coA16 = ((((w & 3) << 6) + lane) << 4);   // A-source lane offset
    const int kA = w >> 2;                              // kblk (low) for even i
    const int gs = s0 + ((w & 3) << 6) + lane;          // global spatial (exact, <100352)
    const int bimg = gs / 3136, sp = gs % 3136;
    const int ppad = sp + 59 + 2 * (sp / 56);
    const char* xB_lo = xpad + (size_t)(bimg * 32 + kA) * PLANE_B + (size_t)ppad * 16;
    const char* xB_hi = xB_lo + 2 * (size_t)PLANE_B;

    // ---- LDS fragment-read offsets ----
    const int aoff = ((lane >> 4) << 12) + ((wm * 128 + (lane & 15)) << 4);
    const int boff = 32768 + ((lane >> 4) << 12) + ((wn * 64 + (lane & 15)) << 4);

    f32x4 acc[8][4] = {};

#define GLL(SRC, DSTOFF) gll16((const void*)(SRC), (void*)(bufW + (DSTOFF) + w * 1024))

    // ---- prologue: stage tile 0 (tap=0, cp=0) in Q-order 0,2,1,3 ----
    {
        char* bufW = smem;
        const long xo0 = -944L;               // toff(tap0)*16 = -59*16
        const long xo1 = xo0 + 4L * PLANE_B;
        GLL(wt2 + (size_t)kA * 4096 + coA16, 0);                 // Q0
        GLL(wt2 + (size_t)(kA + 2) * 4096 + coA16, 8192);
        GLL(xB_lo + xo0, 32768);                                 // Q2
        GLL(xB_hi + xo0, 40960);
        GLL(wt2 + (size_t)(4 + kA) * 4096 + coA16, 16384);       // Q1
        GLL(wt2 + (size_t)(6 + kA) * 4096 + coA16, 24576);
        GLL(xB_lo + xo1, 49152);                                 // Q3
        GLL(xB_hi + xo1, 57344);
        asm volatile("s_waitcnt vmcnt(4)" ::: "memory");
        __builtin_amdgcn_sched_barrier(0);
        __builtin_amdgcn_s_barrier();
    }

    int tap = 0, cp = 0;
    for (int t = 0; t < 36; ++t) {
        const char* bR = smem + ((t & 1) << 16);
        char* bufW = smem + (((t + 1) & 1) << 16);
        // next-tile scalars
        int ntap = tap + 1, ncp = cp;
        if (ntap == 9) { ntap = 0; ncp = cp + 1; }
        const int  ntoff  = (ntap / 3) * 58 + (ntap % 3) - 59;
        const long nwbase = (long)(ntap * 8 + ncp * 2) * 16384;
        const long nxoff0 = (long)ncp * 8 * PLANE_B + (long)ntoff * 16;
        const long nxoff1 = nxoff0 + 4L * PLANE_B;
        const bool st = (t < 35);

        s16x8 af[4], bfr[4];
        // ================= phase 0: cc'0, m 0..3 =================
#pragma unroll
        for (int mi = 0; mi < 4; ++mi) af[mi]  = *(const s16x8*)(bR + aoff + mi * 256);
#pragma unroll
        for (int n = 0; n < 4; ++n)    bfr[n] = *(const s16x8*)(bR + boff + n * 256);
        if (st) {
            GLL(wt2 + nwbase + (size_t)kA * 4096 + coA16, 0);            // Q0
            GLL(wt2 + nwbase + (size_t)(kA + 2) * 4096 + coA16, 8192);
        }
        __builtin_amdgcn_s_barrier();
        asm volatile("s_waitcnt lgkmcnt(0)" ::: "memory");
        __builtin_amdgcn_sched_barrier(0);
        __builtin_amdgcn_s_setprio(1);
#pragma unroll
        for (int mi = 0; mi < 4; ++mi)
#pragma unroll
            for (int n = 0; n < 4; ++n)
                acc[mi][n] = __builtin_amdgcn_mfma_f32_16x16x32_bf16(
                    __builtin_bit_cast(bf16x8, af[mi]),
                    __builtin_bit_cast(bf16x8, bfr[n]), acc[mi][n], 0, 0, 0);
        __builtin_amdgcn_s_setprio(0);
        __builtin_amdgcn_s_barrier();
        // ================= phase 1: cc'0, m 4..7 =================
#pragma unroll
        for (int mi = 0; mi < 4; ++mi)
            af[mi] = *(const s16x8*)(bR + aoff + 1024 + mi * 256);
        if (st) {
            GLL(xB_lo + nxoff0, 32768);                                  // Q2
            GLL(xB_hi + nxoff0, 40960);
        }
        __builtin_amdgcn_s_barrier();
        asm volatile("s_waitcnt lgkmcnt(0)" ::: "memory");
        __builtin_amdgcn_sched_barrier(0);
        __builtin_amdgcn_s_setprio(1);
#pragma unroll
        for (int mi = 0; mi < 4; ++mi)
#pragma unroll
            for (int n = 0; n < 4; ++n)
                acc[4 + mi][n] = __builtin_amdgcn_mfma_f32_16x16x32_bf16(
                    __builtin_bit_cast(bf16x8, af[mi]),
                    __builtin_bit_cast(bf16x8, bfr[n]), acc[4 + mi][n], 0, 0, 0);
        __builtin_amdgcn_s_setprio(0);
        if (st) { asm volatile("s_waitcnt vmcnt(4)" ::: "memory"); }     // Q1,Q3(t) landed
        else    { asm volatile("s_waitcnt vmcnt(0)" ::: "memory"); }
        __builtin_amdgcn_sched_barrier(0);
        __builtin_amdgcn_s_barrier();
        // ================= phase 2: cc'1, m 0..3 =================
#pragma unroll
        for (int mi = 0; mi < 4; ++mi)
            af[mi]  = *(const s16x8*)(bR + 16384 + aoff + mi * 256);
#pragma unroll
        for (int n = 0; n < 4; ++n)
            bfr[n] = *(const s16x8*)(bR + 16384 + boff + n * 256);
        if (st) {
            GLL(wt2 + nwbase + (size_t)(4 + kA) * 4096 + coA16, 16384);  // Q1
            GLL(wt2 + nwbase + (size_t)(6 + kA) * 4096 + coA16, 24576);
        }
        __builtin_amdgcn_s_barrier();
        asm volatile("s_waitcnt lgkmcnt(0)" ::: "memory");
        __builtin_amdgcn_sched_barrier(0);
        __builtin_amdgcn_s_setprio(1);
#pragma unroll
        for (int mi = 0; mi < 4; ++mi)
#pragma unroll
            for (int n = 0; n < 4; ++n)
                acc[mi][n] = __builtin_amdgcn_mfma_f32_16x16x32_bf16(
                    __builtin_bit_cast(bf16x8, af[mi]),
                    __builtin_bit_cast(bf16x8, bfr[n]), acc[mi][n], 0, 0, 0);
        __builtin_amdgcn_s_setprio(0);
        __builtin_amdgcn_s_barrier();
        // ================= phase 3: cc'1, m 4..7 =================
#pragma unroll
        for (int mi = 0; mi < 4; ++mi)
            af[mi] = *(const s16x8*)(bR + 16384 + aoff + 1024 + mi * 256);
        if (st) {
            GLL(xB_lo + nxoff1, 49152);                                  // Q3
            GLL(xB_hi + nxoff1, 57344);
        }
        __builtin_amdgcn_s_barrier();
        asm volatile("s_waitcnt lgkmcnt(0)" ::: "memory");
        __builtin_amdgcn_sched_barrier(0);
        __builtin_amdgcn_s_setprio(1);
#pragma unroll
        for (int mi = 0; mi < 4; ++mi)
#pragma unroll
            for (int n = 0; n < 4; ++n)
                acc[4 + mi][n] = __builtin_amdgcn_mfma_f32_16x16x32_bf16(
                    __builtin_bit_cast(bf16x8, af[mi]),
                    __builtin_bit_cast(bf16x8, bfr[n]), acc[4 + mi][n], 0, 0, 0);
        __builtin_amdgcn_s_setprio(0);
        asm volatile("s_waitcnt vmcnt(4)" ::: "memory");                 // Q0,Q2(t+1) landed
        __builtin_amdgcn_sched_barrier(0);
        __builtin_amdgcn_s_barrier();
        tap = ntap; cp = ncp;
    }
#undef GLL

    // ---- epilogue: raw-conv store + per-(b,co) sum / per-co sumsq ----
    const int row_l = lane >> 4, col_l = lane & 15;
    const int gbase = s0 + wn * 64 + col_l;
    int bN[4]; size_t ybase[4];
#pragma unroll
    for (int n = 0; n < 4; ++n) {
        const int g = gbase + n * 16;
        const int bb = g / 3136, ss = g % 3136;     // b uniform per (wave,n): 3136%16==0
        bN[n] = bb;
        ybase[n] = (size_t)bb * 256 * 3136 + ss;
    }
    const int b0 = bN[0], b3 = bN[3];
    const bool bsplit = (b3 != b0);
    const int cobase = wm * 128 + row_l * 4;
#pragma unroll
    for (int m = 0; m < 8; ++m) {
#pragma unroll
        for (int r = 0; r < 4; ++r) {
            const int co = cobase + m * 16 + r;
            float ls0 = 0.f, ls1 = 0.f, lq = 0.f;
#pragma unroll
            for (int n = 0; n < 4; ++n) {
                const float v = acc[m][n][r];
                y[ybase[n] + (size_t)co * 3136] = v;
                lq += v * v;
                if (bN[n] == b0) ls0 += v; else ls1 += v;
            }
#pragma unroll
            for (int d = 1; d < 16; d <<= 1) {
                ls0 += __shfl_xor(ls0, d, 64);
                lq  += __shfl_xor(lq,  d, 64);
            }
            if (bsplit) {
#pragma unroll
                for (int d = 1; d < 16; d <<= 1) ls1 += __shfl_xor(ls1, d, 64);
            }
            if (col_l == 0) {
                atomicAdd(&Sb[b0 * 256 + co], ls0);
                atomicAdd(&sumsq[co], lq);
                if (bsplit) atomicAdd(&Sb[b3 * 256 + co], ls1);
            }
        }
    }
}

// ---------------- K3: BN finalize (1 block, 256 threads) ----------------
// mean/var over conv+bias, from per-(b,co) conv sums + per-co conv sumsq:
//   sum   = sum_b (S_b + beta_b*N_s);  sumsq = sum(c^2) + sum_b (2 beta_b S_b + beta_b^2 N_s)
__global__ void bn_finalize(const float* __restrict__ stats,
                            const float* __restrict__ gamma,
                            const float* __restrict__ beta,
                            float* __restrict__ scale,
                            float* __restrict__ shiftb) {
    const int co = threadIdx.x;
    const float* Sb   = stats;
    const float* ssq  = stats + 8192;
    const float* bias = stats + 8448;
    float tot = 0.f, tsq = ssq[co];
#pragma unroll 4
    for (int b = 0; b < 32; ++b) {
        const float S = Sb[b * 256 + co], bb = bias[b * 256 + co];
        tot += S + bb * 3136.f;
        tsq += 2.f * bb * S + bb * bb * 3136.f;
    }
    const float inv_n = 1.f / 100352.f;
    const float mean = tot * inv_n;
    const float var  = tsq * inv_n - mean * mean;
    const float sc   = gamma[co] * rsqrtf(var + 1e-5f);
    scale[co] = sc;
    const float bt = beta[co];
    for (int b = 0; b < 32; ++b)
        shiftb[b * 256 + co] = (bias[b * 256 + co] - mean) * sc + bt;
}

// ---------------- K4: in-place BN apply + ReLU ----------------
__global__ __launch_bounds__(256) void bn_apply(float* __restrict__ y,
                                                const float* __restrict__ scale,
                                                const float* __restrict__ shiftb) {
    const size_t i = (size_t)blockIdx.x * 256 + threadIdx.x;  // 6,422,528 float4s
    const int row = (int)(i / 784);                           // = b*256 + co
    const float sc = scale[row & 255], sh = shiftb[row];
    float4 v = ((const float4*)y)[i];
    v.x = fmaxf(v.x * sc + sh, 0.f);
    v.y = fmaxf(v.y * sc + sh, 0.f);
    v.z = fmaxf(v.z * sc + sh, 0.f);
    v.w = fmaxf(v.w * sc + sh, 0.f);
    ((float4*)y)[i] = v;
}

// ---------------- launch ----------------
extern "C" void kernel_launch(void* const* d_in, const int* in_sizes, int n_in,
                              void* d_out, int out_size, void* d_ws, size_t ws_size,
                              hipStream_t stream) {
    const float* x     = (const float*)d_in[0];
    const float* gate  = (const float*)d_in[1];
    const float* W     = (const float*)d_in[2];
    const float* be    = (const float*)d_in[3];
    const float* gamma = (const float*)d_in[4];
    const float* beta  = (const float*)d_in[5];
    float* y  = (float*)d_out;
    char*  ws = (char*)d_ws;

    char*  xpad  = ws;
    char*  wt2   = ws + WT2_OFF;
    float* stats = (float*)(ws + STATS_OFF);
    float* Sb    = stats;
    float* sumsq = stats + 8192;
    float* scale = stats + 16640;
    float* shiftb= stats + 16896;

    hipLaunchKernelGGL(prep_small, dim3(1265),  dim3(256), 0, stream,
                       W, gate, be, xpad, wt2, stats);
    hipLaunchKernelGGL(prep_x,     dim3(32*56), dim3(256), 0, stream, x, gate, xpad);
    hipLaunchKernelGGL(conv_mfma,  dim3(392),   dim3(512), 131072, stream,
                       xpad, wt2, y, Sb, sumsq);
    hipLaunchKernelGGL(bn_finalize,dim3(1),     dim3(256), 0, stream,
                       stats, gamma, beta, scale, shiftb);
    hipLaunchKernelGGL(bn_apply,   dim3(25088), dim3(256), 0, stream,
                       y, scale, shiftb);
}

// Round 6
// 468.376 us; speedup vs baseline: 1.2643x; 1.2643x over previous
//
#include <hip/hip_runtime.h>
#include <cstdint>
#include <cstddef>

// ---------------- constants ----------------
#define S_IMG   3136            // 56*56
#define PPOS    3364            // 58*58 padded positions
#define PLANE_B (PPOS * 16)     // 53824 bytes per (b,cc,kblk) plane
#define XPAD_BYTES (32 * 8 * 4 * PLANE_B)        // 55,115,776
#define WT2_OFF    XPAD_BYTES
#define WT2_BYTES  (9 * 8 * 4 * 256 * 16)        // 1,179,648
#define STATS_OFF  (WT2_OFF + WT2_BYTES)         // 56,295,424
// stats region (floats): sums[256] @0, sumsq[256] @256, bias[32*256] @512
#define ZERO_U4    ((STATS_OFF + 8704 * 4) / 16) // zero ws[0 .. stats end) as uint4

typedef __bf16 bf16x8 __attribute__((ext_vector_type(8)));
typedef short  s16x8  __attribute__((ext_vector_type(8)));
typedef float  f32x4  __attribute__((ext_vector_type(4)));

__device__ __forceinline__ unsigned short f2bf(float f) {
    unsigned u = __float_as_uint(f);
    u += 0x7fffu + ((u >> 16) & 1u);   // round-to-nearest-even
    return (unsigned short)(u >> 16);
}

__device__ __forceinline__ void gll16(const void* g, void* l) {
    __builtin_amdgcn_global_load_lds(
        (const __attribute__((address_space(1))) void*)g,
        (__attribute__((address_space(3))) void*)l, 16, 0, 0);
}

// ---------------- K0: coalesced zero of xpad + wt2 + stats ----------------
__global__ __launch_bounds__(256) void zero_ws(uint4* __restrict__ ws) {
    const uint4 z = make_uint4(0u, 0u, 0u, 0u);
    for (size_t i = (size_t)blockIdx.x * 256 + threadIdx.x; i < (size_t)ZERO_U4;
         i += (size_t)gridDim.x * 256)
        ws[i] = z;
}

// ---------------- K1a: W transpose + bias GEMV ----------------
// grid 320 blocks: [0,288) prep_w, [288,320) prep_bias
__global__ __launch_bounds__(256) void prep_small(const float* __restrict__ W,
                                                  const float* __restrict__ gate,
                                                  const float* __restrict__ be,
                                                  char* __restrict__ wt2,
                                                  float* __restrict__ stats) {
    const int blk = blockIdx.x;
    if (blk < 288) {
        const int g = blk * 256 + threadIdx.x;
        if (g >= 9 * 256 * 32) return;
        const int ci8 = g % 32;                   // = cc*4 + kblk
        const int co  = (g / 32) % 256;
        const int tap = g / (32 * 256);
        const float* src = W + ((size_t)co * 256 + ci8 * 8) * 9 + tap;
        unsigned short v[8];
#pragma unroll
        for (int j = 0; j < 8; ++j) v[j] = f2bf(src[j * 9]);
        uint4 o;
        o.x = (unsigned)v[0] | ((unsigned)v[1] << 16);
        o.y = (unsigned)v[2] | ((unsigned)v[3] << 16);
        o.z = (unsigned)v[4] | ((unsigned)v[5] << 16);
        o.w = (unsigned)v[6] | ((unsigned)v[7] << 16);
        *(uint4*)(wt2 + ((size_t)(tap * 32 + ci8) * 256 + co) * 16) = o;
    } else {
        const int b = blk - 288, co = threadIdx.x;
        const float* gb = gate + b * 256;
        float s = 0.f;
        for (int ci = 0; ci < 256; ++ci) s += gb[ci] * be[ci * 256 + co];
        stats[512 + b * 256 + co] = s;            // bias[b][co]
    }
}

// ---------------- K1b: x*gate -> bf16 padded layout, direct (no LDS) ----------
// grid 1024 blocks = (b, cg) with cg = cc*4+kblk; plane holds ci in [cg*8, cg*8+8)
__global__ __launch_bounds__(256) void prep_x(const float* __restrict__ x,
                                              const float* __restrict__ gate,
                                              char* __restrict__ xpad) {
    const int b  = blockIdx.x >> 5, cg = blockIdx.x & 31;
    const int ci0 = cg * 8;
    const float* xp = x + ((size_t)b * 256 + ci0) * S_IMG;
    float g[8];
#pragma unroll
    for (int j = 0; j < 8; ++j) g[j] = gate[b * 256 + ci0 + j];
    char* dst = xpad + (size_t)(b * 32 + cg) * PLANE_B;
#pragma unroll 2
    for (int i = 0; i < 13; ++i) {
        const int pos = i * 256 + threadIdx.x;
        if (pos < S_IMG) {
            unsigned short v[8];
#pragma unroll
            for (int j = 0; j < 8; ++j) v[j] = f2bf(xp[(size_t)j * S_IMG + pos] * g[j]);
            uint4 o;
            o.x = (unsigned)v[0] | ((unsigned)v[1] << 16);
            o.y = (unsigned)v[2] | ((unsigned)v[3] << 16);
            o.z = (unsigned)v[4] | ((unsigned)v[5] << 16);
            o.w = (unsigned)v[6] | ((unsigned)v[7] << 16);
            const int ppad = pos + 59 + 2 * (pos / 56);   // (h+1)*58 + (w+1)
            *(uint4*)(dst + (size_t)ppad * 16) = o;
        }
    }
}

// ---------------- K2: implicit-GEMM conv, bf16 MFMA, 128x128 tile --------------
// grid 1600 blocks (XCD-swizzled), 256 threads (4 waves 2x2)
// pipeline: 3 LDS buffers, counted vmcnt, ONE raw barrier per k-step  [R2-proven]
__global__ __launch_bounds__(256) void conv_mfma(
    const char* __restrict__ xpad, const char* __restrict__ wt2,
    const float* __restrict__ biasws, float* __restrict__ y,
    float* __restrict__ sums, float* __restrict__ sumsq) {
    __shared__ __align__(16) char smem[49152];   // 3 x (A 8KB | B 8KB)
    const int tid = threadIdx.x;
    const int lane = tid & 63, wave = tid >> 6;
    const int wm = wave >> 1, wn = wave & 1;

    // XCD-aware swizzle: both co-tiles of a (b,s-tile) pair land adjacent on
    // the same XCD (1600 % 8 == 0, bijective).
    const int L = blockIdx.x;
    const int xcd = L & 7, j = L >> 3;        // j in [0,200)
    const int p   = xcd * 100 + (j >> 1);     // pair id in [0,800)
    const int co0 = (j & 1) * 128;
    const int b   = p / 25;
    const int s0  = (p % 25) * 128;

    // per-lane padded positions for the two 64-wide s halves (clamped tail)
    int sA = s0 + lane;       if (sA > S_IMG - 1) sA = S_IMG - 1;
    int sB = s0 + 64 + lane;  if (sB > S_IMG - 1) sB = S_IMG - 1;
    const int pA = sA + 59 + 2 * (sA / 56);   // (h+1)*58 + (w+1)
    const int pB = sB + 59 + 2 * (sB / 56);

    // LDS fragment-read byte offsets (within a buffer)
    const int a_off = ((lane >> 4) * 2048) + (wm * 64 + (lane & 15)) * 16;
    const int b_off = 8192 + ((lane >> 4) * 2048) + (wn * 64 + (lane & 15)) * 16;

    f32x4 acc[4][4] = {};

    const char* xbase = xpad + (size_t)(b * 32 + wave) * PLANE_B; // kblk = wave

    // k-order: tap INNER (k = cc*9 + tap) so the 9 taps of one (b,cc) plane
    // hit the same ~8KB window in 9 consecutive k-steps -> L1/L2-hot.
    auto stage = [&](int k, int bufidx) {
        const int cc = k / 9, tap = k - cc * 9;
        const int off = (tap / 3) * 58 + (tap % 3) - 59;   // dh*58+dw
        char* abase = smem + bufidx * 16384 + wave * 2048; // A plane kblk=wave
        char* bbase = abase + 8192;
        const char* asrc = wt2 + (size_t)((tap * 8 + cc) * 4 + wave) * 4096;
        gll16(asrc + (co0 + lane) * 16,      abase);
        gll16(asrc + (co0 + 64 + lane) * 16, abase + 1024);
        const char* bsrc = xbase + (size_t)cc * 4 * PLANE_B;
        gll16(bsrc + (pA + off) * 16, bbase);
        gll16(bsrc + (pB + off) * 16, bbase + 1024);
    };

    stage(0, 0);
    stage(1, 1);            // own outstanding VMEM: 8

#pragma unroll 3
    for (int k = 0; k < 72; ++k) {
        // wait for OWN stage(k) (4 oldest loads); stage(k+1) stays in flight
        if (k < 70) asm volatile("s_waitcnt vmcnt(4)" ::: "memory");
        else        asm volatile("s_waitcnt vmcnt(0)" ::: "memory");
        __builtin_amdgcn_sched_barrier(0);
        __builtin_amdgcn_s_barrier();         // all waves' stage(k) landed;
        __builtin_amdgcn_sched_barrier(0);    // all reads of buf[(k+2)%3] done (iter k-1)
        if (k + 2 < 72) stage(k + 2, (k + 2) % 3);

        const char* base = smem + (k % 3) * 16384;
        s16x8 af[4], bfr[4];
#pragma unroll
        for (int m = 0; m < 4; ++m) af[m]  = *(const s16x8*)(base + a_off + m * 256);
#pragma unroll
        for (int n = 0; n < 4; ++n) bfr[n] = *(const s16x8*)(base + b_off + n * 256);
        __builtin_amdgcn_s_setprio(1);
#pragma unroll
        for (int m = 0; m < 4; ++m)
#pragma unroll
            for (int n = 0; n < 4; ++n)
                acc[m][n] = __builtin_amdgcn_mfma_f32_16x16x32_bf16(
                    __builtin_bit_cast(bf16x8, af[m]),
                    __builtin_bit_cast(bf16x8, bfr[n]),
                    acc[m][n], 0, 0, 0);
        __builtin_amdgcn_s_setprio(0);
    }

    // epilogue: bias add, y store, per-channel partial stats
    const int row_l = lane >> 4, col_l = lane & 15;
#pragma unroll
    for (int m = 0; m < 4; ++m) {
#pragma unroll
        for (int r = 0; r < 4; ++r) {
            const int co = co0 + wm * 64 + m * 16 + row_l * 4 + r;
            const float bv = biasws[b * 256 + co];
            float lsum = 0.f, lsq = 0.f;
#pragma unroll
            for (int n = 0; n < 4; ++n) {
                const int s = s0 + wn * 64 + n * 16 + col_l;
                if (s < S_IMG) {
                    const float v = acc[m][n][r] + bv;
                    y[(size_t)(b * 256 + co) * S_IMG + s] = v;
                    lsum += v; lsq += v * v;
                }
            }
#pragma unroll
            for (int d = 1; d < 16; d <<= 1) {
                lsum += __shfl_xor(lsum, d, 64);
                lsq  += __shfl_xor(lsq,  d, 64);
            }
            if (col_l == 0) {
                atomicAdd(&sums[co],  lsum);
                atomicAdd(&sumsq[co], lsq);
            }
        }
    }
}

// ---------------- K3: BN finalize folded in + apply + ReLU (in place) ---------
__global__ __launch_bounds__(256) void bn_apply(float* __restrict__ y,
                                                const float* __restrict__ sums,
                                                const float* __restrict__ sumsq,
                                                const float* __restrict__ gamma,
                                                const float* __restrict__ beta) {
    const size_t i = (size_t)blockIdx.x * 256 + threadIdx.x;  // 6,422,528 float4s
    const int co = (int)((i / 784) & 255);
    const float inv_n = 1.f / (float)(32 * S_IMG);
    const float mean = sums[co] * inv_n;
    const float var  = sumsq[co] * inv_n - mean * mean;
    const float sc   = gamma[co] * rsqrtf(var + 1e-5f);
    const float sh   = beta[co] - mean * sc;
    float4 v = ((const float4*)y)[i];
    v.x = fmaxf(v.x * sc + sh, 0.f);
    v.y = fmaxf(v.y * sc + sh, 0.f);
    v.z = fmaxf(v.z * sc + sh, 0.f);
    v.w = fmaxf(v.w * sc + sh, 0.f);
    ((float4*)y)[i] = v;
}

// ---------------- launch ----------------
extern "C" void kernel_launch(void* const* d_in, const int* in_sizes, int n_in,
                              void* d_out, int out_size, void* d_ws, size_t ws_size,
                              hipStream_t stream) {
    const float* x     = (const float*)d_in[0];
    const float* gate  = (const float*)d_in[1];
    const float* W     = (const float*)d_in[2];
    const float* be    = (const float*)d_in[3];
    const float* gamma = (const float*)d_in[4];
    const float* beta  = (const float*)d_in[5];
    float* y  = (float*)d_out;
    char*  ws = (char*)d_ws;

    char*  xpad  = ws;
    char*  wt2   = ws + WT2_OFF;
    float* stats = (float*)(ws + STATS_OFF);
    float* sums  = stats;
    float* sumsq = stats + 256;
    float* bias  = stats + 512;

    hipLaunchKernelGGL(zero_ws,    dim3(2048),  dim3(256), 0, stream, (uint4*)ws);
    hipLaunchKernelGGL(prep_small, dim3(320),   dim3(256), 0, stream,
                       W, gate, be, wt2, stats);
    hipLaunchKernelGGL(prep_x,     dim3(1024),  dim3(256), 0, stream, x, gate, xpad);
    hipLaunchKernelGGL(conv_mfma,  dim3(1600),  dim3(256), 0, stream,
                       xpad, wt2, bias, y, sums, sumsq);
    hipLaunchKernelGGL(bn_apply,   dim3(25088), dim3(256), 0, stream,
                       y, sums, sumsq, gamma, beta);
}